// Round 3
// baseline (570.877 us; speedup 1.0000x reference)
//
#include <hip/hip_runtime.h>
#include <stdint.h>

#define B_   4
#define SQ_  4096
#define SKV_ 4096
#define D_   1024

typedef __attribute__((ext_vector_type(4))) float f32x4;
typedef __attribute__((ext_vector_type(8))) short bf8_t;

__device__ __forceinline__ unsigned short f2bf(float f) {
    unsigned u = __float_as_uint(f);
    u += 0x7fff + ((u >> 16) & 1);   // RNE; inputs are finite
    return (unsigned short)(u >> 16);
}

__device__ __forceinline__ void gload_lds16(const void* g, void* l) {
    __builtin_amdgcn_global_load_lds(
        (const __attribute__((address_space(1))) unsigned int*)g,
        (__attribute__((address_space(3))) unsigned int*)l,
        16, 0, 0);
}

__device__ __forceinline__ void barrier_mem() {
    asm volatile("" ::: "memory");
    __builtin_amdgcn_s_barrier();
    asm volatile("" ::: "memory");
}

// ---------------- fp32 -> bf16 convert (vectorized) ----------------
__global__ void cvt_f32_bf16_kernel(const float* __restrict__ in,
                                    unsigned short* __restrict__ out, int n4) {
    int stride = gridDim.x * blockDim.x;
    for (int i = blockIdx.x * blockDim.x + threadIdx.x; i < n4; i += stride) {
        float4 v = ((const float4*)in)[i];
        ushort4 o;
        o.x = f2bf(v.x); o.y = f2bf(v.y); o.z = f2bf(v.z); o.w = f2bf(v.w);
        ((ushort4*)out)[i] = o;
    }
}

// ---------------- V [Skv][D] fp32  ->  VT [D][Skv] bf16 ----------------
__global__ void transpose_cvt_kernel(const float* __restrict__ V,
                                     unsigned short* __restrict__ VT) {
    __shared__ float tile[32][33];
    int b = blockIdx.z;
    const float* Vb = V + (size_t)b * SKV_ * D_;
    unsigned short* VTb = VT + (size_t)b * D_ * SKV_;
    int d0 = blockIdx.x * 32, k0 = blockIdx.y * 32;
    int x = threadIdx.x, y = threadIdx.y;   // block (32,8)
    #pragma unroll
    for (int i = 0; i < 4; ++i)
        tile[y + i * 8][x] = Vb[(size_t)(k0 + y + i * 8) * D_ + d0 + x];
    __syncthreads();
    #pragma unroll
    for (int i = 0; i < 4; ++i)
        VTb[(size_t)(d0 + y + i * 8) * SKV_ + k0 + x] = f2bf(tile[x][y + i * 8]);
}

// ================= 256x256 8-phase bf16 NT GEMM ==========
// C[m][n] = scale * sum_k A[m][k]*B[n][k] (+ mask[n]).  BK=64, 8 waves (2Mx4N).
// LDS 128 KiB = 2 dbuf x {A,B} x 2 kk-halves x 16 KiB, stored FRAGMENT-MAJOR:
// region [buf][kk] holds o16 = (panel, frag, lane) -> 16B chunk, so every
// ds_read_b128 is lane*16 contiguous (canonical conflict-free), and staging
// achieves this via a remapped per-thread GLOBAL source (linear LDS dest,
// required by global_load_lds).  Counted vmcnt(6) once per K-tile; raw
// barriers + setprio(1) around each 16-MFMA cluster.
__global__ __launch_bounds__(512, 2) void gemm256_nt_bf16_kernel(
    const unsigned short* __restrict__ A, int lda, size_t strideA,
    const unsigned short* __restrict__ Bm, int ldb, size_t strideB,
    float* __restrict__ C, int ldc, size_t strideC,
    int K, float scale, const float* __restrict__ mask)
{
    __shared__ __align__(16) unsigned char smem[131072];

    const int tid  = threadIdx.x;
    const int lane = tid & 63, wid = tid >> 6;
    const int wr = wid >> 2, wc = wid & 3;       // 2 M-halves x 4 N-quarters

    // bijective XCD swizzle (gridDim.x*gridDim.y divisible by 8 here)
    int lin  = blockIdx.y * gridDim.x + blockIdx.x;
    int q8   = (gridDim.x * gridDim.y) >> 3;
    int lin2 = (lin & 7) * q8 + (lin >> 3);
    int bn = lin2 % gridDim.x, bm = lin2 / gridDim.x;
    int bz = blockIdx.z;

    const char* Ab = (const char*)(A + (size_t)bz * strideA);
    const char* Bb = (const char*)(Bm + (size_t)bz * strideB);
    float* Cb = C + (size_t)bz * strideC;
    const int ldaB = lda * 2, ldbB = ldb * 2;

    // ---- staging per-thread constants (fragment-major global source) ----
    // load j covers LDS o16 = j*512 + tid:
    //   row = j*128 + (tid>>6)*16 + (tid&15),  col-chunk = ((tid>>4)&3)*16 B
    const int srow = ((tid >> 6) * 16) + (tid & 15);
    const int scol = ((tid >> 4) & 3) * 16;
    const char* Apan = Ab + (size_t)(bm * 256 + srow) * ldaB + scol;
    const char* Bpan = Bb + (size_t)(bn * 256 + srow) * ldbB + scol;
    char* ldsA = (char*)smem;            // [buf][kk]: 2 x 2 x 16 KiB
    char* ldsB = (char*)smem + 65536;

    // ---- fragment reads: pure lane*16 contiguous ----
    const char* aRd = (char*)smem + wr * 8192 + lane * 16;
    const char* bRd = (char*)smem + 65536 + wc * 4096 + lane * 16;

    f32x4 acc[8][4] = {};
    const int NT = K >> 6;

#define STAGE_A(tt, hh) do { \
    const char* s_ = Apan + (tt) * 128 + (hh) * 64; \
    char* d_ = ldsA + (((tt) & 1) * 32768) + (hh) * 16384 + tid * 16; \
    gload_lds16(s_, d_); \
    gload_lds16(s_ + (size_t)128 * ldaB, d_ + 8192); \
} while (0)
#define STAGE_B(tt, hh) do { \
    const char* s_ = Bpan + (tt) * 128 + (hh) * 64; \
    char* d_ = ldsB + (((tt) & 1) * 32768) + (hh) * 16384 + tid * 16; \
    gload_lds16(s_, d_); \
    gload_lds16(s_ + (size_t)128 * ldbB, d_ + 8192); \
} while (0)

    // ---- prologue: tile0 complete + 3 halves of tile1; drain to 6 in flight ----
    STAGE_A(0, 0); STAGE_A(0, 1); STAGE_B(0, 0); STAGE_B(0, 1);
    if (NT > 1) {
        STAGE_A(1, 0); STAGE_B(1, 0); STAGE_B(1, 1);
        asm volatile("s_waitcnt vmcnt(6)" ::: "memory");
    } else {
        asm volatile("s_waitcnt vmcnt(0)" ::: "memory");
    }
    barrier_mem();

    for (int t = 0; t < NT; ++t) {
        const int p = t & 1;
        const char* aT = aRd + p * 32768;
        const char* bT = bRd + p * 32768;
        bf8_t a0[8], a1[8], b0[4], b1[4];

        // -------- phase 1: read A(kk0) x8 + B(kk0) x4; stage Ah1(t+1) --------
        #pragma unroll
        for (int m = 0; m < 8; ++m) a0[m] = *(const bf8_t*)(aT + m * 1024);
        #pragma unroll
        for (int n = 0; n < 4; ++n) b0[n] = *(const bf8_t*)(bT + n * 1024);
        if (t + 1 < NT) STAGE_A(t + 1, 1);
        barrier_mem();
        __builtin_amdgcn_s_setprio(1);
        #pragma unroll
        for (int m = 0; m < 4; ++m)
            #pragma unroll
            for (int n = 0; n < 4; ++n)
                acc[m][n] = __builtin_amdgcn_mfma_f32_16x16x32_bf16(a0[m], b0[n], acc[m][n], 0, 0, 0);
        __builtin_amdgcn_s_setprio(0);
        barrier_mem();

        // -------- phase 2: read B(kk1) x4; stage Ah0(t+2) --------
        #pragma unroll
        for (int n = 0; n < 4; ++n) b1[n] = *(const bf8_t*)(bT + 16384 + n * 1024);
        if (t + 2 < NT) STAGE_A(t + 2, 0);
        barrier_mem();
        __builtin_amdgcn_s_setprio(1);
        #pragma unroll
        for (int m = 0; m < 4; ++m)
            #pragma unroll
            for (int n = 0; n < 4; ++n)
                acc[m + 4][n] = __builtin_amdgcn_mfma_f32_16x16x32_bf16(a0[m + 4], b0[n], acc[m + 4][n], 0, 0, 0);
        __builtin_amdgcn_s_setprio(0);
        barrier_mem();

        // -------- phase 3: read A(kk1) x8; stage Bh0(t+2) --------
        #pragma unroll
        for (int m = 0; m < 8; ++m) a1[m] = *(const bf8_t*)(aT + 16384 + m * 1024);
        if (t + 2 < NT) STAGE_B(t + 2, 0);
        barrier_mem();
        __builtin_amdgcn_s_setprio(1);
        #pragma unroll
        for (int m = 0; m < 4; ++m)
            #pragma unroll
            for (int n = 0; n < 4; ++n)
                acc[m][n] = __builtin_amdgcn_mfma_f32_16x16x32_bf16(a1[m], b1[n], acc[m][n], 0, 0, 0);
        __builtin_amdgcn_s_setprio(0);
        barrier_mem();

        // -------- phase 4: stage Bh1(t+2); counted vmcnt once per tile --------
        if (t + 2 < NT) STAGE_B(t + 2, 1);
        barrier_mem();
        __builtin_amdgcn_s_setprio(1);
        #pragma unroll
        for (int m = 0; m < 4; ++m)
            #pragma unroll
            for (int n = 0; n < 4; ++n)
                acc[m + 4][n] = __builtin_amdgcn_mfma_f32_16x16x32_bf16(a1[m + 4], b1[n], acc[m + 4][n], 0, 0, 0);
        __builtin_amdgcn_s_setprio(0);
        if (t + 2 < NT)      asm volatile("s_waitcnt vmcnt(6)" ::: "memory");
        else if (t + 1 < NT) asm volatile("s_waitcnt vmcnt(0)" ::: "memory");
        barrier_mem();
    }
#undef STAGE_A
#undef STAGE_B

    // ---- epilogue: C/D layout col=lane&15, row=(lane>>4)*4+reg ----
    const int row0 = bm * 256 + wr * 128 + (lane >> 4) * 4;
    const int col0 = bn * 256 + wc * 64 + (lane & 15);
    const float* maskb = mask ? mask + (size_t)bz * SKV_ : nullptr;
    #pragma unroll
    for (int n = 0; n < 4; ++n) {
        int col = col0 + n * 16;
        float mk = maskb ? maskb[col] : 0.0f;
        #pragma unroll
        for (int m = 0; m < 8; ++m) {
            int row = row0 + m * 16;
            #pragma unroll
            for (int r = 0; r < 4; ++r)
                Cb[(size_t)(row + r) * ldc + col] = acc[m][n][r] * scale + mk;
        }
    }
}

// ---------------- row softmax in place + optional bf16 copy ----------------
__global__ __launch_bounds__(256) void softmax_kernel(float* __restrict__ scores,
                                                      unsigned short* __restrict__ abf) {
    __shared__ __align__(16) float buf[SKV_];
    __shared__ float red[4];
    size_t row = blockIdx.x;
    float* p = scores + row * SKV_;
    int t = threadIdx.x;

    float lmax = -3.4e38f;
    for (int i = t * 4; i < SKV_; i += 1024) {
        float4 v = *(const float4*)(p + i);
        *(float4*)&buf[i] = v;
        lmax = fmaxf(fmaxf(lmax, fmaxf(v.x, v.y)), fmaxf(v.z, v.w));
    }
    #pragma unroll
    for (int o = 32; o; o >>= 1) lmax = fmaxf(lmax, __shfl_down(lmax, o));
    if ((t & 63) == 0) red[t >> 6] = lmax;
    __syncthreads();
    float rmax = fmaxf(fmaxf(red[0], red[1]), fmaxf(red[2], red[3]));
    __syncthreads();

    float lsum = 0.f;
    for (int i = t * 4; i < SKV_; i += 1024) {
        float4 v = *(const float4*)&buf[i];
        v.x = __expf(v.x - rmax); v.y = __expf(v.y - rmax);
        v.z = __expf(v.z - rmax); v.w = __expf(v.w - rmax);
        *(float4*)&buf[i] = v;
        lsum += (v.x + v.y) + (v.z + v.w);
    }
    #pragma unroll
    for (int o = 32; o; o >>= 1) lsum += __shfl_down(lsum, o);
    if ((t & 63) == 0) red[t >> 6] = lsum;
    __syncthreads();
    float rinv = 1.0f / ((red[0] + red[1]) + (red[2] + red[3]));

    unsigned short* ab = abf ? abf + row * SKV_ : nullptr;
    for (int i = t * 4; i < SKV_; i += 1024) {
        float4 v = *(const float4*)&buf[i];
        v.x *= rinv; v.y *= rinv; v.z *= rinv; v.w *= rinv;
        *(float4*)(p + i) = v;
        if (ab) {
            ushort4 o;
            o.x = f2bf(v.x); o.y = f2bf(v.y); o.z = f2bf(v.z); o.w = f2bf(v.w);
            *(ushort4*)(ab + i) = o;
        }
    }
}

// ---------------- naive fallback path (used only if ws too small) ----------------
__global__ void naive_nt_kernel(const float* __restrict__ A, const float* __restrict__ Bm,
                                float* __restrict__ C, const float* __restrict__ mask,
                                int N, int K, float scale) {
    __shared__ float As[16][16], Bs[16][16];
    int b = blockIdx.z;
    const float* Ab = A + (size_t)b * SQ_ * K;
    const float* Bb = Bm + (size_t)b * N * K;
    float* Cb = C + (size_t)b * SQ_ * N;
    int tx = threadIdx.x, ty = threadIdx.y;
    int m = blockIdx.y * 16 + ty, n = blockIdx.x * 16 + tx;
    float acc = 0.f;
    for (int k0 = 0; k0 < K; k0 += 16) {
        As[ty][tx] = Ab[(size_t)m * K + k0 + tx];
        Bs[ty][tx] = Bb[(size_t)(blockIdx.x * 16 + ty) * K + k0 + tx];
        __syncthreads();
        #pragma unroll
        for (int kk = 0; kk < 16; ++kk) acc += As[ty][kk] * Bs[tx][kk];
        __syncthreads();
    }
    Cb[(size_t)m * N + n] = acc * scale + (mask ? mask[(size_t)b * SKV_ + n] : 0.f);
}

__global__ void naive_nn_kernel(const float* __restrict__ A, const float* __restrict__ Bm,
                                float* __restrict__ C, int N, int K) {
    __shared__ float As[16][16], Bs[16][17];
    int b = blockIdx.z;
    const float* Ab = A + (size_t)b * SQ_ * K;
    const float* Bb = Bm + (size_t)b * K * N;
    float* Cb = C + (size_t)b * SQ_ * N;
    int tx = threadIdx.x, ty = threadIdx.y;
    int m = blockIdx.y * 16 + ty, n = blockIdx.x * 16 + tx;
    float acc = 0.f;
    for (int k0 = 0; k0 < K; k0 += 16) {
        As[ty][tx] = Ab[(size_t)m * K + k0 + tx];
        Bs[ty][tx] = Bb[(size_t)(k0 + ty) * N + n];
        __syncthreads();
        #pragma unroll
        for (int kk = 0; kk < 16; ++kk) acc += As[ty][kk] * Bs[kk][tx];
        __syncthreads();
    }
    Cb[(size_t)m * N + n] = acc;
}

extern "C" void kernel_launch(void* const* d_in, const int* in_sizes, int n_in,
                              void* d_out, int out_size, void* d_ws, size_t ws_size,
                              hipStream_t stream) {
    const float* q    = (const float*)d_in[0];
    const float* kv   = (const float*)d_in[1];
    const float* mask = (const float*)d_in[2];
    // d_in[3] = layer_idx: compression rate 1.0 at layer 0 -> identity, unused.

    float* out  = (float*)d_out;
    float* attn = out + (size_t)B_ * SQ_ * D_;   // outputs: (out, attn) concatenated
    const float scale = 0.03125f;                // 1/sqrt(1024)

    size_t nQ    = (size_t)B_ * SQ_ * D_;
    size_t nKV   = (size_t)B_ * SKV_ * D_;
    size_t nAttn = (size_t)B_ * SQ_ * SKV_;
    size_t need  = (nQ + nKV + nKV + nAttn) * 2;   // qbf + kbf + vtbf + abf

    if (ws_size >= need) {
        unsigned short* qbf  = (unsigned short*)d_ws;
        unsigned short* kbf  = qbf + nQ;
        unsigned short* vtbf = kbf + nKV;
        unsigned short* abf  = vtbf + nKV;

        cvt_f32_bf16_kernel<<<2048, 256, 0, stream>>>(q, qbf, (int)(nQ / 4));
        cvt_f32_bf16_kernel<<<2048, 256, 0, stream>>>(kv, kbf, (int)(nKV / 4));
        transpose_cvt_kernel<<<dim3(D_ / 32, SKV_ / 32, B_), dim3(32, 8), 0, stream>>>(kv, vtbf);

        // scores = scale * Q K^T + mask  (raw, pre-softmax) into attn region
        gemm256_nt_bf16_kernel<<<dim3(SKV_ / 256, SQ_ / 256, B_), 512, 0, stream>>>(
            qbf, D_, (size_t)SQ_ * D_,
            kbf, D_, (size_t)SKV_ * D_,
            attn, SKV_, (size_t)SQ_ * SKV_,
            D_, scale, mask);

        softmax_kernel<<<B_ * SQ_, 256, 0, stream>>>(attn, abf);

        // out = attn @ V  ==  NT gemm with B = V^T  [D][Skv]
        gemm256_nt_bf16_kernel<<<dim3(D_ / 256, SQ_ / 256, B_), 512, 0, stream>>>(
            abf, SKV_, (size_t)SQ_ * SKV_,
            vtbf, SKV_, (size_t)D_ * SKV_,
            out, D_, (size_t)SQ_ * D_,
            SKV_, 1.0f, nullptr);
    } else {
        // insurance path: no scratch required
        naive_nt_kernel<<<dim3(SKV_ / 16, SQ_ / 16, B_), dim3(16, 16), 0, stream>>>(
            q, kv, attn, mask, SKV_, D_, scale);
        softmax_kernel<<<B_ * SQ_, 256, 0, stream>>>(attn, nullptr);
        naive_nn_kernel<<<dim3(D_ / 16, SQ_ / 16, B_), dim3(16, 16), 0, stream>>>(
            attn, kv, out, D_, SKV_);
    }
}

// Round 4
// 482.753 us; speedup vs baseline: 1.1825x; 1.1825x over previous
//
#include <hip/hip_runtime.h>
#include <hip/hip_fp16.h>
#include <stdint.h>

#define B_   4
#define SQ_  4096
#define SKV_ 4096
#define D_   1024

typedef __attribute__((ext_vector_type(4))) float f32x4;
typedef __attribute__((ext_vector_type(8))) short bf8_t;

__device__ __forceinline__ unsigned short f2bf(float f) {
    unsigned u = __float_as_uint(f);
    u += 0x7fff + ((u >> 16) & 1);   // RNE; inputs are finite
    return (unsigned short)(u >> 16);
}

__device__ __forceinline__ void gload_lds16(const void* g, void* l) {
    __builtin_amdgcn_global_load_lds(
        (const __attribute__((address_space(1))) unsigned int*)g,
        (__attribute__((address_space(3))) unsigned int*)l,
        16, 0, 0);
}

__device__ __forceinline__ void barrier_mem() {
    asm volatile("" ::: "memory");
    __builtin_amdgcn_s_barrier();
    asm volatile("" ::: "memory");
}

// ---------------- fp32 -> bf16 convert (vectorized) ----------------
__global__ void cvt_f32_bf16_kernel(const float* __restrict__ in,
                                    unsigned short* __restrict__ out, int n4) {
    int stride = gridDim.x * blockDim.x;
    for (int i = blockIdx.x * blockDim.x + threadIdx.x; i < n4; i += stride) {
        float4 v = ((const float4*)in)[i];
        ushort4 o;
        o.x = f2bf(v.x); o.y = f2bf(v.y); o.z = f2bf(v.z); o.w = f2bf(v.w);
        ((ushort4*)out)[i] = o;
    }
}

// ------- fused: KV f32 -> Kbf (bf16, same layout) + VT (bf16, transposed) -------
__global__ void cvtkv_kernel(const float* __restrict__ V,
                             unsigned short* __restrict__ Kbf,
                             unsigned short* __restrict__ VT) {
    __shared__ float tile[32][33];
    int b = blockIdx.z;
    const float* Vb = V + (size_t)b * SKV_ * D_;
    unsigned short* Kb = Kbf + (size_t)b * SKV_ * D_;
    unsigned short* VTb = VT + (size_t)b * D_ * SKV_;
    int d0 = blockIdx.x * 32, k0 = blockIdx.y * 32;
    int x = threadIdx.x, y = threadIdx.y;   // block (32,8)
    #pragma unroll
    for (int i = 0; i < 4; ++i) {
        float v = Vb[(size_t)(k0 + y + i * 8) * D_ + d0 + x];
        tile[y + i * 8][x] = v;
        Kb[(size_t)(k0 + y + i * 8) * D_ + d0 + x] = f2bf(v);
    }
    __syncthreads();
    #pragma unroll
    for (int i = 0; i < 4; ++i)
        VTb[(size_t)(d0 + y + i * 8) * SKV_ + k0 + x] = f2bf(tile[x][y + i * 8]);
}

// ================= 256x256 8-phase PIPELINED bf16 NT GEMM ==========
// C[m][n] = scale * sum_k A[m][k]*B[n][k] (+ mask[n]).  BK=64, 8 waves (2Mx4N).
// Fragment-major LDS (every ds_read_b128 = lane*16 contiguous, conflict-free).
// CROSS-PHASE pipeline: ds_reads issued in phase p (after its barrier) feed
// phase p+1's MFMA -> compiler emits counted lgkm waits; read burst hides
// under the MFMA cluster.  Counted vmcnt(8) at P2/P4 (drains exactly the 4
// loads whose data that phase's reads touch); stage slots chosen so each LDS
// region's last pending reads drain >=1 barrier before its re-write issues.
template<bool HALF_OUT>
__global__ __launch_bounds__(512, 2) void gemm256_pipe_kernel(
    const unsigned short* __restrict__ A, int lda, size_t strideA,
    const unsigned short* __restrict__ Bm, int ldb, size_t strideB,
    void* __restrict__ Cv, int ldc, size_t strideC,
    int K, float scale, const float* __restrict__ mask)
{
    __shared__ __align__(16) unsigned char smem[131072];

    const int tid  = threadIdx.x;
    const int lane = tid & 63, wid = tid >> 6;
    const int wr = wid >> 2, wc = wid & 3;       // 2 M-halves x 4 N-quarters

    // bijective XCD swizzle (gridDim.x*gridDim.y divisible by 8 here)
    int lin  = blockIdx.y * gridDim.x + blockIdx.x;
    int q8   = (gridDim.x * gridDim.y) >> 3;
    int lin2 = (lin & 7) * q8 + (lin >> 3);
    int bn = lin2 % gridDim.x, bm = lin2 / gridDim.x;
    int bz = blockIdx.z;

    const char* Ab = (const char*)(A + (size_t)bz * strideA);
    const char* Bb = (const char*)(Bm + (size_t)bz * strideB);
    const int ldaB = lda * 2, ldbB = ldb * 2;

    // staging source (fragment-major map): load j covers LDS o16 = j*512 + tid
    const int srow = ((tid >> 6) * 16) + (tid & 15);
    const int scol = ((tid >> 4) & 3) * 16;
    const char* Apan = Ab + (size_t)(bm * 256 + srow) * ldaB + scol;
    const char* Bpan = Bb + (size_t)(bn * 256 + srow) * ldbB + scol;
    char* ldsA = (char*)smem;            // [buf][kk]: 2 x 2 x 16 KiB
    char* ldsB = (char*)smem + 65536;

    // fragment reads: pure lane*16 contiguous
    const char* aRd = (char*)smem + wr * 8192 + lane * 16;
    const char* bRd = (char*)smem + 65536 + wc * 4096 + lane * 16;

    f32x4 acc[8][4] = {};
    const int NT = K >> 6;

#define STAGE_A(tt, hh) do { \
    const char* s_ = Apan + (tt) * 128 + (hh) * 64; \
    char* d_ = ldsA + (((tt) & 1) * 32768) + (hh) * 16384 + tid * 16; \
    gload_lds16(s_, d_); \
    gload_lds16(s_ + (size_t)128 * ldaB, d_ + 8192); \
} while (0)
#define STAGE_B(tt, hh) do { \
    const char* s_ = Bpan + (tt) * 128 + (hh) * 64; \
    char* d_ = ldsB + (((tt) & 1) * 32768) + (hh) * 16384 + tid * 16; \
    gload_lds16(s_, d_); \
    gload_lds16(s_ + (size_t)128 * ldbB, d_ + 8192); \
} while (0)
#define MFMA16(ACCBASE, AF, BF) do { \
    __builtin_amdgcn_s_setprio(1); \
    _Pragma("unroll") \
    for (int m_ = 0; m_ < 4; ++m_) \
        _Pragma("unroll") \
        for (int n_ = 0; n_ < 4; ++n_) \
            acc[(ACCBASE) + m_][n_] = __builtin_amdgcn_mfma_f32_16x16x32_bf16( \
                AF[m_], BF[n_], acc[(ACCBASE) + m_][n_], 0, 0, 0); \
    __builtin_amdgcn_s_setprio(0); \
} while (0)

    // ---- prologue: tile0 (B00,A00,B01,A01) + 3 halves of tile1 ----
    STAGE_B(0, 0); STAGE_A(0, 0); STAGE_B(0, 1); STAGE_A(0, 1);
    if (NT > 1) {
        STAGE_B(1, 0); STAGE_A(1, 0); STAGE_B(1, 1);
        asm volatile("s_waitcnt vmcnt(10)" ::: "memory");   // drain B00,A00
    } else {
        asm volatile("s_waitcnt vmcnt(0)" ::: "memory");
    }
    barrier_mem();

    bf8_t aL[4], aH[4], bA[4], bB[4];
    #pragma unroll
    for (int m = 0; m < 4; ++m) aL[m] = *(const bf8_t*)(aRd + m * 1024);
    #pragma unroll
    for (int n = 0; n < 4; ++n) bA[n] = *(const bf8_t*)(bRd + n * 1024);

    for (int t = 0; t < NT; ++t) {
        const int p = t & 1;
        const char* aT = aRd + p * 32768;
        const char* bT = bRd + p * 32768;

        // ---- P1: stage A(t+1,1); MFMA acc[0..3] = aL(kk0)*bA(kk0); read aH(kk0)
        if (t + 1 < NT) STAGE_A(t + 1, 1);
        barrier_mem();
        #pragma unroll
        for (int m = 0; m < 4; ++m) aH[m] = *(const bf8_t*)(aT + (4 + m) * 1024);
        MFMA16(0, aL, bA);
        barrier_mem();

        // ---- P2: vmcnt(8) [drains A(t,1),B(t,1)]; stage B(t+2,0);
        //          MFMA acc[4..7] = aH*bA; read aL(kk1), bB(kk1)
        if (t == NT - 1) asm volatile("s_waitcnt vmcnt(0)" ::: "memory");
        else             asm volatile("s_waitcnt vmcnt(8)" ::: "memory");
        if (t + 2 < NT) STAGE_B(t + 2, 0);
        barrier_mem();
        #pragma unroll
        for (int m = 0; m < 4; ++m) aL[m] = *(const bf8_t*)(aT + 16384 + m * 1024);
        #pragma unroll
        for (int n = 0; n < 4; ++n) bB[n] = *(const bf8_t*)(bT + 16384 + n * 1024);
        MFMA16(4, aH, bA);
        barrier_mem();

        // ---- P3: stage A(t+2,0); MFMA acc[0..3] = aL(kk1)*bB(kk1); read aH(kk1)
        if (t + 2 < NT) STAGE_A(t + 2, 0);
        barrier_mem();
        #pragma unroll
        for (int m = 0; m < 4; ++m) aH[m] = *(const bf8_t*)(aT + 16384 + (4 + m) * 1024);
        MFMA16(0, aL, bB);
        barrier_mem();

        // ---- P4: vmcnt(8)/(4) [drains A(t+1,0),B(t+1,0)]; stage B(t+2,1);
        //          MFMA acc[4..7] = aH*bB; read next tile's aL(kk0), bA(kk0)
        if (t + 2 < NT) {
            asm volatile("s_waitcnt vmcnt(8)" ::: "memory");
            STAGE_B(t + 2, 1);
        } else if (t + 1 < NT) {
            asm volatile("s_waitcnt vmcnt(4)" ::: "memory");
        }
        barrier_mem();
        if (t + 1 < NT) {
            const char* aTn = aRd + (p ^ 1) * 32768;
            const char* bTn = bRd + (p ^ 1) * 32768;
            #pragma unroll
            for (int m = 0; m < 4; ++m) aL[m] = *(const bf8_t*)(aTn + m * 1024);
            #pragma unroll
            for (int n = 0; n < 4; ++n) bA[n] = *(const bf8_t*)(bTn + n * 1024);
        }
        MFMA16(4, aH, bB);
        barrier_mem();
    }
#undef STAGE_A
#undef STAGE_B
#undef MFMA16

    // ---- epilogue: C/D layout col=lane&15, row=(lane>>4)*4+reg ----
    const int row0 = bm * 256 + wr * 128 + (lane >> 4) * 4;
    const int col0 = bn * 256 + wc * 64 + (lane & 15);
    if (HALF_OUT) {
        __half* Ch = (__half*)Cv + (size_t)bz * strideC;
        const float* maskb = mask + (size_t)bz * SKV_;
        #pragma unroll
        for (int n = 0; n < 4; ++n) {
            int col = col0 + n * 16;
            float mk = maskb[col];
            #pragma unroll
            for (int m = 0; m < 8; ++m) {
                int row = row0 + m * 16;
                #pragma unroll
                for (int r = 0; r < 4; ++r)
                    Ch[(size_t)(row + r) * ldc + col] = __float2half(acc[m][n][r] * scale + mk);
            }
        }
    } else {
        float* Cf = (float*)Cv + (size_t)bz * strideC;
        #pragma unroll
        for (int n = 0; n < 4; ++n) {
            int col = col0 + n * 16;
            #pragma unroll
            for (int m = 0; m < 8; ++m) {
                int row = row0 + m * 16;
                #pragma unroll
                for (int r = 0; r < 4; ++r)
                    Cf[(size_t)(row + r) * ldc + col] = acc[m][n][r];
            }
        }
    }
}

// ------- row softmax: read fp16 scores, write fp32 attn + bf16 in-place -------
__global__ __launch_bounds__(256) void softmax_kernel(unsigned short* __restrict__ s2,
                                                      float* __restrict__ attn) {
    __shared__ __align__(16) float buf[SKV_];
    __shared__ float red[4];
    size_t row = blockIdx.x;
    unsigned short* p = s2 + row * SKV_;
    float* ao = attn + row * SKV_;
    int t = threadIdx.x;

    float lmax = -3.4e38f;
    for (int i = t * 8; i < SKV_; i += 2048) {
        uint4 hv = *(const uint4*)(p + i);
        float2 f0 = __half22float2(*(__half2*)&hv.x);
        float2 f1 = __half22float2(*(__half2*)&hv.y);
        float2 f2 = __half22float2(*(__half2*)&hv.z);
        float2 f3 = __half22float2(*(__half2*)&hv.w);
        buf[i+0] = f0.x; buf[i+1] = f0.y; buf[i+2] = f1.x; buf[i+3] = f1.y;
        buf[i+4] = f2.x; buf[i+5] = f2.y; buf[i+6] = f3.x; buf[i+7] = f3.y;
        lmax = fmaxf(lmax, fmaxf(fmaxf(fmaxf(f0.x, f0.y), fmaxf(f1.x, f1.y)),
                                 fmaxf(fmaxf(f2.x, f2.y), fmaxf(f3.x, f3.y))));
    }
    #pragma unroll
    for (int o = 32; o; o >>= 1) lmax = fmaxf(lmax, __shfl_down(lmax, o));
    if ((t & 63) == 0) red[t >> 6] = lmax;
    __syncthreads();
    float rmax = fmaxf(fmaxf(red[0], red[1]), fmaxf(red[2], red[3]));
    __syncthreads();

    float lsum = 0.f;
    for (int i = t * 4; i < SKV_; i += 1024) {
        float4 v = *(const float4*)&buf[i];
        v.x = __expf(v.x - rmax); v.y = __expf(v.y - rmax);
        v.z = __expf(v.z - rmax); v.w = __expf(v.w - rmax);
        *(float4*)&buf[i] = v;
        lsum += (v.x + v.y) + (v.z + v.w);
    }
    #pragma unroll
    for (int o = 32; o; o >>= 1) lsum += __shfl_down(lsum, o);
    if ((t & 63) == 0) red[t >> 6] = lsum;
    __syncthreads();
    float rinv = 1.0f / ((red[0] + red[1]) + (red[2] + red[3]));

    for (int i = t * 8; i < SKV_; i += 2048) {
        float4 v0 = *(const float4*)&buf[i];
        float4 v1 = *(const float4*)&buf[i + 4];
        v0.x *= rinv; v0.y *= rinv; v0.z *= rinv; v0.w *= rinv;
        v1.x *= rinv; v1.y *= rinv; v1.z *= rinv; v1.w *= rinv;
        *(float4*)(ao + i) = v0;
        *(float4*)(ao + i + 4) = v1;
        ushort4 o0, o1;
        o0.x = f2bf(v0.x); o0.y = f2bf(v0.y); o0.z = f2bf(v0.z); o0.w = f2bf(v0.w);
        o1.x = f2bf(v1.x); o1.y = f2bf(v1.y); o1.z = f2bf(v1.z); o1.w = f2bf(v1.w);
        *(ushort4*)(p + i) = o0;           // in-place: same row this block read
        *(ushort4*)(p + i + 4) = o1;
    }
}

// ---------------- naive fallback path (used only if ws too small) ----------------
__global__ __launch_bounds__(256) void softmax_f32_kernel(float* __restrict__ scores) {
    __shared__ __align__(16) float buf[SKV_];
    __shared__ float red[4];
    size_t row = blockIdx.x;
    float* p = scores + row * SKV_;
    int t = threadIdx.x;
    float lmax = -3.4e38f;
    for (int i = t * 4; i < SKV_; i += 1024) {
        float4 v = *(const float4*)(p + i);
        *(float4*)&buf[i] = v;
        lmax = fmaxf(fmaxf(lmax, fmaxf(v.x, v.y)), fmaxf(v.z, v.w));
    }
    #pragma unroll
    for (int o = 32; o; o >>= 1) lmax = fmaxf(lmax, __shfl_down(lmax, o));
    if ((t & 63) == 0) red[t >> 6] = lmax;
    __syncthreads();
    float rmax = fmaxf(fmaxf(red[0], red[1]), fmaxf(red[2], red[3]));
    __syncthreads();
    float lsum = 0.f;
    for (int i = t * 4; i < SKV_; i += 1024) {
        float4 v = *(const float4*)&buf[i];
        v.x = __expf(v.x - rmax); v.y = __expf(v.y - rmax);
        v.z = __expf(v.z - rmax); v.w = __expf(v.w - rmax);
        *(float4*)&buf[i] = v;
        lsum += (v.x + v.y) + (v.z + v.w);
    }
    #pragma unroll
    for (int o = 32; o; o >>= 1) lsum += __shfl_down(lsum, o);
    if ((t & 63) == 0) red[t >> 6] = lsum;
    __syncthreads();
    float rinv = 1.0f / ((red[0] + red[1]) + (red[2] + red[3]));
    for (int i = t * 4; i < SKV_; i += 1024) {
        float4 v = *(const float4*)&buf[i];
        v.x *= rinv; v.y *= rinv; v.z *= rinv; v.w *= rinv;
        *(float4*)(p + i) = v;
    }
}

__global__ void naive_nt_kernel(const float* __restrict__ A, const float* __restrict__ Bm,
                                float* __restrict__ C, const float* __restrict__ mask,
                                int N, int K, float scale) {
    __shared__ float As[16][16], Bs[16][16];
    int b = blockIdx.z;
    const float* Ab = A + (size_t)b * SQ_ * K;
    const float* Bb = Bm + (size_t)b * N * K;
    float* Cb = C + (size_t)b * SQ_ * N;
    int tx = threadIdx.x, ty = threadIdx.y;
    int m = blockIdx.y * 16 + ty, n = blockIdx.x * 16 + tx;
    float acc = 0.f;
    for (int k0 = 0; k0 < K; k0 += 16) {
        As[ty][tx] = Ab[(size_t)m * K + k0 + tx];
        Bs[ty][tx] = Bb[(size_t)(blockIdx.x * 16 + ty) * K + k0 + tx];
        __syncthreads();
        #pragma unroll
        for (int kk = 0; kk < 16; ++kk) acc += As[ty][kk] * Bs[tx][kk];
        __syncthreads();
    }
    Cb[(size_t)m * N + n] = acc * scale + (mask ? mask[(size_t)b * SKV_ + n] : 0.f);
}

__global__ void naive_nn_kernel(const float* __restrict__ A, const float* __restrict__ Bm,
                                float* __restrict__ C, int N, int K) {
    __shared__ float As[16][16], Bs[16][17];
    int b = blockIdx.z;
    const float* Ab = A + (size_t)b * SQ_ * K;
    const float* Bb = Bm + (size_t)b * K * N;
    float* Cb = C + (size_t)b * SQ_ * N;
    int tx = threadIdx.x, ty = threadIdx.y;
    int m = blockIdx.y * 16 + ty, n = blockIdx.x * 16 + tx;
    float acc = 0.f;
    for (int k0 = 0; k0 < K; k0 += 16) {
        As[ty][tx] = Ab[(size_t)m * K + k0 + tx];
        Bs[ty][tx] = Bb[(size_t)(k0 + ty) * N + n];
        __syncthreads();
        #pragma unroll
        for (int kk = 0; kk < 16; ++kk) acc += As[ty][kk] * Bs[kk][tx];
        __syncthreads();
    }
    Cb[(size_t)m * N + n] = acc;
}

extern "C" void kernel_launch(void* const* d_in, const int* in_sizes, int n_in,
                              void* d_out, int out_size, void* d_ws, size_t ws_size,
                              hipStream_t stream) {
    const float* q    = (const float*)d_in[0];
    const float* kv   = (const float*)d_in[1];
    const float* mask = (const float*)d_in[2];
    // d_in[3] = layer_idx: compression rate 1.0 at layer 0 -> identity, unused.

    float* out  = (float*)d_out;
    float* attn = out + (size_t)B_ * SQ_ * D_;   // outputs: (out, attn) concatenated
    const float scale = 0.03125f;                // 1/sqrt(1024)

    size_t nQ    = (size_t)B_ * SQ_ * D_;
    size_t nKV   = (size_t)B_ * SKV_ * D_;
    size_t nAttn = (size_t)B_ * SQ_ * SKV_;
    size_t need  = (nQ + nKV + nKV + nAttn) * 2;   // qbf + kbf + vtbf + s2

    if (ws_size >= need) {
        unsigned short* qbf  = (unsigned short*)d_ws;
        unsigned short* kbf  = qbf + nQ;
        unsigned short* vtbf = kbf + nKV;
        unsigned short* s2   = vtbf + nKV;   // fp16 scores -> (in-place) bf16 attn

        cvt_f32_bf16_kernel<<<2048, 256, 0, stream>>>(q, qbf, (int)(nQ / 4));
        cvtkv_kernel<<<dim3(D_ / 32, SKV_ / 32, B_), dim3(32, 8), 0, stream>>>(kv, kbf, vtbf);

        // scores = scale * Q K^T + mask  -> fp16 in ws
        gemm256_pipe_kernel<true><<<dim3(SKV_ / 256, SQ_ / 256, B_), 512, 0, stream>>>(
            qbf, D_, (size_t)SQ_ * D_,
            kbf, D_, (size_t)SKV_ * D_,
            (void*)s2, SKV_, (size_t)SQ_ * SKV_,
            D_, scale, mask);

        // softmax: fp16 scores -> fp32 attn (d_out) + bf16 attn (in-place in ws)
        softmax_kernel<<<B_ * SQ_, 256, 0, stream>>>(s2, attn);

        // out = attn @ V  ==  NT gemm with A = attn(bf16), B = V^T [D][Skv]
        gemm256_pipe_kernel<false><<<dim3(D_ / 256, SQ_ / 256, B_), 512, 0, stream>>>(
            s2, SKV_, (size_t)SQ_ * SKV_,
            vtbf, SKV_, (size_t)D_ * SKV_,
            (void*)out, D_, (size_t)SQ_ * D_,
            SKV_, 1.0f, nullptr);
    } else {
        // insurance path: no scratch required
        naive_nt_kernel<<<dim3(SKV_ / 16, SQ_ / 16, B_), dim3(16, 16), 0, stream>>>(
            q, kv, attn, mask, SKV_, D_, scale);
        softmax_f32_kernel<<<B_ * SQ_, 256, 0, stream>>>(attn);
        naive_nn_kernel<<<dim3(D_ / 16, SQ_ / 16, B_), dim3(16, 16), 0, stream>>>(
            attn, kv, out, D_, SKV_);
    }
}

// Round 5
// 482.454 us; speedup vs baseline: 1.1833x; 1.0006x over previous
//
#include <hip/hip_runtime.h>
#include <hip/hip_fp16.h>
#include <stdint.h>

#define B_   4
#define SQ_  4096
#define SKV_ 4096
#define D_   1024

typedef __attribute__((ext_vector_type(4))) float f32x4;
typedef __attribute__((ext_vector_type(8))) short bf8_t;

__device__ __forceinline__ unsigned short f2bf(float f) {
    unsigned u = __float_as_uint(f);
    u += 0x7fff + ((u >> 16) & 1);   // RNE; inputs are finite
    return (unsigned short)(u >> 16);
}

__device__ __forceinline__ void gload_lds16(const void* g, void* l) {
    __builtin_amdgcn_global_load_lds(
        (const __attribute__((address_space(1))) unsigned int*)g,
        (__attribute__((address_space(3))) unsigned int*)l,
        16, 0, 0);
}

// ---------------- fp32 -> bf16 convert (vectorized) ----------------
__global__ void cvt_f32_bf16_kernel(const float* __restrict__ in,
                                    unsigned short* __restrict__ out, int n4) {
    int stride = gridDim.x * blockDim.x;
    for (int i = blockIdx.x * blockDim.x + threadIdx.x; i < n4; i += stride) {
        float4 v = ((const float4*)in)[i];
        ushort4 o;
        o.x = f2bf(v.x); o.y = f2bf(v.y); o.z = f2bf(v.z); o.w = f2bf(v.w);
        ((ushort4*)out)[i] = o;
    }
}

// ------- fused: KV f32 -> Kbf (bf16, same layout) + VT (bf16, transposed) -------
__global__ void cvtkv_kernel(const float* __restrict__ V,
                             unsigned short* __restrict__ Kbf,
                             unsigned short* __restrict__ VT) {
    __shared__ float tile[32][33];
    int b = blockIdx.z;
    const float* Vb = V + (size_t)b * SKV_ * D_;
    unsigned short* Kb = Kbf + (size_t)b * SKV_ * D_;
    unsigned short* VTb = VT + (size_t)b * D_ * SKV_;
    int d0 = blockIdx.x * 32, k0 = blockIdx.y * 32;
    int x = threadIdx.x, y = threadIdx.y;   // block (32,8)
    #pragma unroll
    for (int i = 0; i < 4; ++i) {
        float v = Vb[(size_t)(k0 + y + i * 8) * D_ + d0 + x];
        tile[y + i * 8][x] = v;
        Kb[(size_t)(k0 + y + i * 8) * D_ + d0 + x] = f2bf(v);
    }
    __syncthreads();
    #pragma unroll
    for (int i = 0; i < 4; ++i)
        VTb[(size_t)(d0 + y + i * 8) * SKV_ + k0 + x] = f2bf(tile[x][y + i * 8]);
}

// ================= 128x128 m97-structure bf16 NT GEMM, 3 blocks/CU ==========
// C[m][n] = scale * sum_k A[m][k]*B[n][k] (+ mask[n]).  BK=64, 4 waves (2Mx2N),
// 32 KiB single-buffered LDS, stage -> sync -> compute -> sync per K-step.
// TLP across 3 resident blocks/CU hides the staging drain (m97/m114 mechanism).
// Fragment-major LDS: chunk o16 = ((kk*128 + r)<<2) | k-subgroup, so every
// ds_read_b128 is a contiguous-1KiB wave access (conflict-free) AND every
// gload_lds wave-write is contiguous (linear dest required by the instr).
template<bool HALF_OUT>
__global__ __launch_bounds__(256, 3) void gemm128_kernel(
    const unsigned short* __restrict__ A, int lda, size_t strideA,
    const unsigned short* __restrict__ Bm, int ldb, size_t strideB,
    void* __restrict__ Cv, int ldc, size_t strideC,
    int K, float scale, const float* __restrict__ mask)
{
    __shared__ __align__(16) unsigned char smem[32768];   // A 16K | B 16K

    const int tid  = threadIdx.x;
    const int lane = tid & 63, wid = tid >> 6;
    const int wr = wid >> 1, wc = wid & 1;

    // bijective XCD swizzle (gridDim.x*gridDim.y divisible by 8 here)
    int lin  = blockIdx.y * gridDim.x + blockIdx.x;
    int q8   = (gridDim.x * gridDim.y) >> 3;
    int lin2 = (lin & 7) * q8 + (lin >> 3);
    int bn = lin2 % gridDim.x, bm = lin2 / gridDim.x;
    int bz = blockIdx.z;

    const char* Ab = (const char*)(A + (size_t)bz * strideA);
    const char* Bb = (const char*)(Bm + (size_t)bz * strideB);
    const int ldaB = lda * 2, ldbB = ldb * 2;

    // staging: thread t covers chunks o = q*256+t, q=0..3, per matrix.
    // decode: g=o&3 (16B k-subgroup), r=(o>>2)&127 (row), kk=o>>9 (k-half)
    const char* aSrc[4]; const char* bSrc[4]; int dstOff[4];
    #pragma unroll
    for (int q = 0; q < 4; ++q) {
        int o = q * 256 + tid;
        int g = o & 3, r = (o >> 2) & 127, kk = o >> 9;
        aSrc[q] = Ab + (size_t)(bm * 128 + r) * ldaB + kk * 64 + g * 16;
        bSrc[q] = Bb + (size_t)(bn * 128 + r) * ldbB + kk * 64 + g * 16;
        dstOff[q] = o * 16;
    }
    char* ldsA = (char*)smem;
    char* ldsB = (char*)smem + 16384;

    // fragment reads: byte = kk*8192 + (whalf*64 + m*16 + (lane&15))*64 + (lane>>4)*16
    const int rbase = (lane & 15) * 64 + (lane >> 4) * 16;
    const char* aRd = ldsA + wr * 4096 + rbase;
    const char* bRd = ldsB + wc * 4096 + rbase;

    f32x4 acc[4][4] = {};

    for (int k0 = 0; k0 < K; k0 += 64) {
        #pragma unroll
        for (int q = 0; q < 4; ++q) gload_lds16(aSrc[q], ldsA + dstOff[q]);
        #pragma unroll
        for (int q = 0; q < 4; ++q) gload_lds16(bSrc[q], ldsB + dstOff[q]);
        #pragma unroll
        for (int q = 0; q < 4; ++q) { aSrc[q] += 128; bSrc[q] += 128; }
        __syncthreads();                      // vmcnt(0) drain; TLP covers it
        #pragma unroll
        for (int kk = 0; kk < 2; ++kk) {
            bf8_t af[4], bfv[4];
            #pragma unroll
            for (int m = 0; m < 4; ++m) af[m]  = *(const bf8_t*)(aRd + kk * 8192 + m * 1024);
            #pragma unroll
            for (int n = 0; n < 4; ++n) bfv[n] = *(const bf8_t*)(bRd + kk * 8192 + n * 1024);
            #pragma unroll
            for (int m = 0; m < 4; ++m)
                #pragma unroll
                for (int n = 0; n < 4; ++n)
                    acc[m][n] = __builtin_amdgcn_mfma_f32_16x16x32_bf16(
                        af[m], bfv[n], acc[m][n], 0, 0, 0);
        }
        __syncthreads();
    }

    // epilogue: C/D layout col=lane&15, row=(lane>>4)*4+reg
    const int row0 = bm * 128 + wr * 64 + (lane >> 4) * 4;
    const int col0 = bn * 128 + wc * 64 + (lane & 15);
    if (HALF_OUT) {
        __half* Ch = (__half*)Cv + (size_t)bz * strideC;
        const float* maskb = mask + (size_t)bz * SKV_;
        #pragma unroll
        for (int n = 0; n < 4; ++n) {
            int col = col0 + n * 16;
            float mk = maskb[col];
            #pragma unroll
            for (int m = 0; m < 4; ++m) {
                int row = row0 + m * 16;
                #pragma unroll
                for (int r = 0; r < 4; ++r)
                    Ch[(size_t)(row + r) * ldc + col] = __float2half(acc[m][n][r] * scale + mk);
            }
        }
    } else {
        float* Cf = (float*)Cv + (size_t)bz * strideC;
        #pragma unroll
        for (int n = 0; n < 4; ++n) {
            int col = col0 + n * 16;
            #pragma unroll
            for (int m = 0; m < 4; ++m) {
                int row = row0 + m * 16;
                #pragma unroll
                for (int r = 0; r < 4; ++r)
                    Cf[(size_t)(row + r) * ldc + col] = acc[m][n][r];
            }
        }
    }
}

// ------- row softmax: read fp16 scores, write fp32 attn + bf16 in-place -------
__global__ __launch_bounds__(256) void softmax_kernel(unsigned short* __restrict__ s2,
                                                      float* __restrict__ attn) {
    __shared__ __align__(16) float buf[SKV_];
    __shared__ float red[4];
    size_t row = blockIdx.x;
    unsigned short* p = s2 + row * SKV_;
    float* ao = attn + row * SKV_;
    int t = threadIdx.x;

    float lmax = -3.4e38f;
    for (int i = t * 8; i < SKV_; i += 2048) {
        uint4 hv = *(const uint4*)(p + i);
        float2 f0 = __half22float2(*(__half2*)&hv.x);
        float2 f1 = __half22float2(*(__half2*)&hv.y);
        float2 f2 = __half22float2(*(__half2*)&hv.z);
        float2 f3 = __half22float2(*(__half2*)&hv.w);
        buf[i+0] = f0.x; buf[i+1] = f0.y; buf[i+2] = f1.x; buf[i+3] = f1.y;
        buf[i+4] = f2.x; buf[i+5] = f2.y; buf[i+6] = f3.x; buf[i+7] = f3.y;
        lmax = fmaxf(lmax, fmaxf(fmaxf(fmaxf(f0.x, f0.y), fmaxf(f1.x, f1.y)),
                                 fmaxf(fmaxf(f2.x, f2.y), fmaxf(f3.x, f3.y))));
    }
    #pragma unroll
    for (int o = 32; o; o >>= 1) lmax = fmaxf(lmax, __shfl_down(lmax, o));
    if ((t & 63) == 0) red[t >> 6] = lmax;
    __syncthreads();
    float rmax = fmaxf(fmaxf(red[0], red[1]), fmaxf(red[2], red[3]));
    __syncthreads();

    float lsum = 0.f;
    for (int i = t * 4; i < SKV_; i += 1024) {
        float4 v = *(const float4*)&buf[i];
        v.x = __expf(v.x - rmax); v.y = __expf(v.y - rmax);
        v.z = __expf(v.z - rmax); v.w = __expf(v.w - rmax);
        *(float4*)&buf[i] = v;
        lsum += (v.x + v.y) + (v.z + v.w);
    }
    #pragma unroll
    for (int o = 32; o; o >>= 1) lsum += __shfl_down(lsum, o);
    if ((t & 63) == 0) red[t >> 6] = lsum;
    __syncthreads();
    float rinv = 1.0f / ((red[0] + red[1]) + (red[2] + red[3]));

    for (int i = t * 8; i < SKV_; i += 2048) {
        float4 v0 = *(const float4*)&buf[i];
        float4 v1 = *(const float4*)&buf[i + 4];
        v0.x *= rinv; v0.y *= rinv; v0.z *= rinv; v0.w *= rinv;
        v1.x *= rinv; v1.y *= rinv; v1.z *= rinv; v1.w *= rinv;
        *(float4*)(ao + i) = v0;
        *(float4*)(ao + i + 4) = v1;
        ushort4 o0, o1;
        o0.x = f2bf(v0.x); o0.y = f2bf(v0.y); o0.z = f2bf(v0.z); o0.w = f2bf(v0.w);
        o1.x = f2bf(v1.x); o1.y = f2bf(v1.y); o1.z = f2bf(v1.z); o1.w = f2bf(v1.w);
        *(ushort4*)(p + i) = o0;           // in-place: same row this block read
        *(ushort4*)(p + i + 4) = o1;
    }
}

// ---------------- naive fallback path (used only if ws too small) ----------------
__global__ __launch_bounds__(256) void softmax_f32_kernel(float* __restrict__ scores) {
    __shared__ __align__(16) float buf[SKV_];
    __shared__ float red[4];
    size_t row = blockIdx.x;
    float* p = scores + row * SKV_;
    int t = threadIdx.x;
    float lmax = -3.4e38f;
    for (int i = t * 4; i < SKV_; i += 1024) {
        float4 v = *(const float4*)(p + i);
        *(float4*)&buf[i] = v;
        lmax = fmaxf(fmaxf(lmax, fmaxf(v.x, v.y)), fmaxf(v.z, v.w));
    }
    #pragma unroll
    for (int o = 32; o; o >>= 1) lmax = fmaxf(lmax, __shfl_down(lmax, o));
    if ((t & 63) == 0) red[t >> 6] = lmax;
    __syncthreads();
    float rmax = fmaxf(fmaxf(red[0], red[1]), fmaxf(red[2], red[3]));
    __syncthreads();
    float lsum = 0.f;
    for (int i = t * 4; i < SKV_; i += 1024) {
        float4 v = *(const float4*)&buf[i];
        v.x = __expf(v.x - rmax); v.y = __expf(v.y - rmax);
        v.z = __expf(v.z - rmax); v.w = __expf(v.w - rmax);
        *(float4*)&buf[i] = v;
        lsum += (v.x + v.y) + (v.z + v.w);
    }
    #pragma unroll
    for (int o = 32; o; o >>= 1) lsum += __shfl_down(lsum, o);
    if ((t & 63) == 0) red[t >> 6] = lsum;
    __syncthreads();
    float rinv = 1.0f / ((red[0] + red[1]) + (red[2] + red[3]));
    for (int i = t * 4; i < SKV_; i += 1024) {
        float4 v = *(const float4*)&buf[i];
        v.x *= rinv; v.y *= rinv; v.z *= rinv; v.w *= rinv;
        *(float4*)(p + i) = v;
    }
}

__global__ void naive_nt_kernel(const float* __restrict__ A, const float* __restrict__ Bm,
                                float* __restrict__ C, const float* __restrict__ mask,
                                int N, int K, float scale) {
    __shared__ float As[16][16], Bs[16][16];
    int b = blockIdx.z;
    const float* Ab = A + (size_t)b * SQ_ * K;
    const float* Bb = Bm + (size_t)b * N * K;
    float* Cb = C + (size_t)b * SQ_ * N;
    int tx = threadIdx.x, ty = threadIdx.y;
    int m = blockIdx.y * 16 + ty, n = blockIdx.x * 16 + tx;
    float acc = 0.f;
    for (int k0 = 0; k0 < K; k0 += 16) {
        As[ty][tx] = Ab[(size_t)m * K + k0 + tx];
        Bs[ty][tx] = Bb[(size_t)(blockIdx.x * 16 + ty) * K + k0 + tx];
        __syncthreads();
        #pragma unroll
        for (int kk = 0; kk < 16; ++kk) acc += As[ty][kk] * Bs[tx][kk];
        __syncthreads();
    }
    Cb[(size_t)m * N + n] = acc * scale + (mask ? mask[(size_t)b * SKV_ + n] : 0.f);
}

__global__ void naive_nn_kernel(const float* __restrict__ A, const float* __restrict__ Bm,
                                float* __restrict__ C, int N, int K) {
    __shared__ float As[16][16], Bs[16][17];
    int b = blockIdx.z;
    const float* Ab = A + (size_t)b * SQ_ * K;
    const float* Bb = Bm + (size_t)b * K * N;
    float* Cb = C + (size_t)b * SQ_ * N;
    int tx = threadIdx.x, ty = threadIdx.y;
    int m = blockIdx.y * 16 + ty, n = blockIdx.x * 16 + tx;
    float acc = 0.f;
    for (int k0 = 0; k0 < K; k0 += 16) {
        As[ty][tx] = Ab[(size_t)m * K + k0 + tx];
        Bs[ty][tx] = Bb[(size_t)(k0 + ty) * N + n];
        __syncthreads();
        #pragma unroll
        for (int kk = 0; kk < 16; ++kk) acc += As[ty][kk] * Bs[kk][tx];
        __syncthreads();
    }
    Cb[(size_t)m * N + n] = acc;
}

extern "C" void kernel_launch(void* const* d_in, const int* in_sizes, int n_in,
                              void* d_out, int out_size, void* d_ws, size_t ws_size,
                              hipStream_t stream) {
    const float* q    = (const float*)d_in[0];
    const float* kv   = (const float*)d_in[1];
    const float* mask = (const float*)d_in[2];
    // d_in[3] = layer_idx: compression rate 1.0 at layer 0 -> identity, unused.

    float* out  = (float*)d_out;
    float* attn = out + (size_t)B_ * SQ_ * D_;   // outputs: (out, attn) concatenated
    const float scale = 0.03125f;                // 1/sqrt(1024)

    size_t nQ    = (size_t)B_ * SQ_ * D_;
    size_t nKV   = (size_t)B_ * SKV_ * D_;
    size_t nAttn = (size_t)B_ * SQ_ * SKV_;
    size_t need  = (nQ + nKV + nKV + nAttn) * 2;   // qbf + kbf + vtbf + s2

    if (ws_size >= need) {
        unsigned short* qbf  = (unsigned short*)d_ws;
        unsigned short* kbf  = qbf + nQ;
        unsigned short* vtbf = kbf + nKV;
        unsigned short* s2   = vtbf + nKV;   // fp16 scores -> (in-place) bf16 attn

        cvt_f32_bf16_kernel<<<2048, 256, 0, stream>>>(q, qbf, (int)(nQ / 4));
        cvtkv_kernel<<<dim3(D_ / 32, SKV_ / 32, B_), dim3(32, 8), 0, stream>>>(kv, kbf, vtbf);

        // scores = scale * Q K^T + mask  -> fp16 in ws
        gemm128_kernel<true><<<dim3(SKV_ / 128, SQ_ / 128, B_), 256, 0, stream>>>(
            qbf, D_, (size_t)SQ_ * D_,
            kbf, D_, (size_t)SKV_ * D_,
            (void*)s2, SKV_, (size_t)SQ_ * SKV_,
            D_, scale, mask);

        // softmax: fp16 scores -> fp32 attn (d_out) + bf16 attn (in-place in ws)
        softmax_kernel<<<B_ * SQ_, 256, 0, stream>>>(s2, attn);

        // out = attn @ V  ==  NT gemm with A = attn(bf16), B = V^T [D][Skv]
        gemm128_kernel<false><<<dim3(D_ / 128, SQ_ / 128, B_), 256, 0, stream>>>(
            s2, SKV_, (size_t)SQ_ * SKV_,
            vtbf, SKV_, (size_t)D_ * SKV_,
            (void*)out, D_, (size_t)SQ_ * D_,
            SKV_, 1.0f, nullptr);
    } else {
        // insurance path: no scratch required
        naive_nt_kernel<<<dim3(SKV_ / 16, SQ_ / 16, B_), dim3(16, 16), 0, stream>>>(
            q, kv, attn, mask, SKV_, D_, scale);
        softmax_f32_kernel<<<B_ * SQ_, 256, 0, stream>>>(attn);
        naive_nn_kernel<<<dim3(D_ / 16, SQ_ / 16, B_), dim3(16, 16), 0, stream>>>(
            attn, kv, out, D_, SKV_);
    }
}